// Round 4
// baseline (249.352 us; speedup 1.0000x reference)
//
#include <hip/hip_runtime.h>

#define HWSZ 65536      // H*W
#define KSEL 32768u     // int(0.5*H*W)
#define CCH  128        // channels
#define BN   4          // batch
#define NG   (CCH * BN) // 512 groups; group g = b*CCH + c, contiguous HWSZ floats
#define NT   1024       // threads per block (16 waves) -> 2 blocks/CU = 32 waves/CU
#define NW   (NT / 64)  // 16 waves
#define ITER (HWSZ / 4 / NT)   // 16 float4 iterations per pass

#define NB1  12                // coarse bins: b1 = q>>25 in [0,11] (e < 0.375 always)
#define NB2  1024              // fine bins inside boundary coarse bin (12K effective)
#define QC   (-744261120.0f)   // -ln(2) * 2^30: q = (u32)(f1*log2(f1)*QC + 0.5)
#define SUMMASK ((1ull << 47) - 1ull)   // q30 sum bits[46:0], count bits[63:47]

// Two streaming passes, zero LDS ops in the phase-1 hot loop.
// Phase 1 (HBM): exact q30 total (register u64) + coarse 12-bin count hist held
// in a single u64 register SWAR (5-bit fields, flushed to u16-packed register
// accumulators every <=24 elements; max field value 24 < 31). Reduction is
// shuffle-based — no per-element LDS RMW chain to stall on.
// Phase 2 (L3 re-read): exact q30 sum of coarse bins > cb in registers;
// boundary-bin elements go to a 1024-fine-bin packed (cnt<<47|q30) LDS atomic
// hist (fire-and-forget, no dependent reads). Fine width = 2^-15 in e — same
// binning as the verified round-3 kernel (bit-identical q / b1 / fbin).
__global__ void __launch_bounds__(NT, 8) passA_kernel(
    const float* __restrict__ hsi, const float* __restrict__ wp,
    double* __restrict__ total_sum, double* __restrict__ topk_sum) {
    __shared__ unsigned long long hist2[NB2];      // 8 KB packed fine hist
    __shared__ unsigned wred[NW * 6];              // 384 B wave-level coarse counts
    __shared__ unsigned cnt1[NB1];                 // 48 B
    __shared__ unsigned long long wtot[NW];        // 128 B
    __shared__ unsigned long long whigh[NW];       // 128 B
    __shared__ int s_cb;
    __shared__ unsigned s_acc;                     // exact count strictly above bin cb
    __shared__ int s_fb;
    // total ~10 KB LDS

    const int g    = blockIdx.x;
    const int tid  = threadIdx.x;
    const int lane = tid & 63;
    const int wid  = tid >> 6;
    const float w  = wp[0];

    hist2[tid] = 0ull;                             // NT == NB2; consumed after 2 barriers

    const float4* __restrict__ src = (const float4*)(hsi + (size_t)g * HWSZ);

    // ---- Phase 1: HBM stream — exact q30 total + register-SWAR coarse hist ----
    unsigned long long tot = 0ull;
    unsigned long long sw  = 0ull;                 // 12 x 5-bit count fields
    unsigned acc0 = 0u, acc1 = 0u, acc2 = 0u, acc3 = 0u, acc4 = 0u, acc5 = 0u;

    auto elem = [&](float h) -> unsigned {
        float f1 = h * w;
        float m  = f1 * __log2f(f1);               // v_log_f32 + v_mul
        unsigned q = (unsigned)fmaf(m, QC, 0.5f);  // e*2^30, q < 2^29
        unsigned b1 = q >> 25;                     // coarse bin, <= 11 always
        sw += 1ull << (b1 * 5);                    // register SWAR count
        return q;
    };
    auto proc = [&](int i) {
        float4 v = src[i * NT + tid];
        unsigned qs = elem(v.x) + elem(v.y) + elem(v.z) + elem(v.w);  // 4q < 2^31
        tot += qs;
    };
    auto flush = [&]() {                           // unpack 12x5b -> 6 u16-pair words
        acc0 += (unsigned)( sw        & 31u) | ((unsigned)((sw >>  5) & 31u) << 16);
        acc1 += (unsigned)((sw >> 10) & 31u) | ((unsigned)((sw >> 15) & 31u) << 16);
        acc2 += (unsigned)((sw >> 20) & 31u) | ((unsigned)((sw >> 25) & 31u) << 16);
        acc3 += (unsigned)((sw >> 30) & 31u) | ((unsigned)((sw >> 35) & 31u) << 16);
        acc4 += (unsigned)((sw >> 40) & 31u) | ((unsigned)((sw >> 45) & 31u) << 16);
        acc5 += (unsigned)((sw >> 50) & 31u) | ((unsigned)((sw >> 55) & 31u) << 16);
        sw = 0ull;
    };
    proc(0);  proc(1);  proc(2);  proc(3);  proc(4);  proc(5);  flush();  // 24 el
    proc(6);  proc(7);  proc(8);  proc(9);  proc(10); proc(11); flush();  // 24 el
    proc(12); proc(13); proc(14); proc(15);                     flush();  // 16 el

    // wave-level reductions (u16 fields: max 64 lanes * 64 = 4096 < 65536)
    {
        unsigned accv[6] = {acc0, acc1, acc2, acc3, acc4, acc5};
        #pragma unroll
        for (int k = 0; k < 6; ++k) {
            unsigned a = accv[k];
            #pragma unroll
            for (int off = 32; off > 0; off >>= 1) a += __shfl_down(a, off, 64);
            if (lane == 0) wred[wid * 6 + k] = a;
        }
    }
    #pragma unroll
    for (int off = 32; off > 0; off >>= 1) tot += __shfl_down(tot, off, 64);
    if (lane == 0) wtot[wid] = tot;
    __syncthreads();

    // ---- combine 16 waves -> cnt1[12] ----
    if (tid < NB1) {
        unsigned s = 0u;
        #pragma unroll
        for (int ww = 0; ww < NW; ++ww) {
            unsigned v = wred[ww * 6 + (tid >> 1)];
            s += (tid & 1) ? (v >> 16) : (v & 0xFFFFu);
        }
        cnt1[tid] = s;
    }
    __syncthreads();

    // ---- locate level-1 boundary bin cb (scan from the top; 12 bins) ----
    if (tid == 0) {
        unsigned acc = 0u;
        int b = NB1 - 1;
        for (; b > 0; --b) {
            unsigned c = cnt1[b];
            if (acc + c >= KSEL) break;
            acc += c;
        }
        s_cb = b;
        s_acc = acc;
    }
    __syncthreads();
    const unsigned cb = (unsigned)s_cb;

    // ---- Phase 2: L3-resident re-read — exact high sum + fine hist inside cb ----
    unsigned long long hsum = 0ull;
    #pragma unroll 4
    for (int i = 0; i < ITER; ++i) {
        float4 v = src[i * NT + tid];
        unsigned qs = 0u;
        #pragma unroll
        for (int j = 0; j < 4; ++j) {
            float f1 = (&v.x)[j] * w;
            float m  = f1 * __log2f(f1);
            unsigned q = (unsigned)fmaf(m, QC, 0.5f);   // bit-identical to phase 1
            unsigned b1 = q >> 25;
            qs += (b1 > cb) ? q : 0u;
            if (b1 == cb) {
                unsigned fbin = (q >> 15) & (NB2 - 1);  // exact: 2^25/2^15 = 1024
                atomicAdd(&hist2[fbin], (1ull << 47) | (unsigned long long)q);
            }
        }
        hsum += qs;
    }
    #pragma unroll
    for (int off = 32; off > 0; off >>= 1) hsum += __shfl_down(hsum, off, 64);
    if (lane == 0) whigh[wid] = hsum;
    __syncthreads();

    // ---- in-place parallel suffix scan on packed hist2 (cnt 17b ok, sum < 2^45) ----
    for (int off = 1; off < NB2; off <<= 1) {
        unsigned long long a = hist2[tid];
        unsigned long long b = (tid + off < NB2) ? hist2[tid + off] : 0ull;
        __syncthreads();
        hist2[tid] = a + b;
        __syncthreads();
    }
    const unsigned needed = KSEL - s_acc;          // >= 1 by construction of cb
    {
        unsigned c0 = (unsigned)(hist2[tid] >> 47);
        unsigned c1 = (tid == NB2 - 1) ? 0u : (unsigned)(hist2[tid + 1] >> 47);
        if (c0 >= needed && c1 < needed) s_fb = tid;   // unique crossing: sufc non-increasing
    }
    __syncthreads();

    if (tid == 0) {
        unsigned long long tt = 0ull, hh = 0ull;
        #pragma unroll
        for (int i = 0; i < NW; ++i) { tt += wtot[i]; hh += whigh[i]; }
        total_sum[g] = (double)tt * (1.0 / 1073741824.0);

        const int fb = s_fb;
        unsigned long long above = (fb < NB2 - 1) ? hist2[fb + 1] : 0ull;
        unsigned cA = (unsigned)(above >> 47);
        unsigned long long sA = above & SUMMASK;
        unsigned long long cur = hist2[fb];
        unsigned cf = (unsigned)(cur >> 47) - cA;
        unsigned long long sf = (cur & SUMMASK) - sA;
        // boundary fine bin: (needed-cA) items at the bin's average value.
        double take = (double)(needed - cA);
        double avg  = (cf > 0u) ? ((double)sf / (double)cf) : 0.0;
        topk_sum[g] = ((double)hh + (double)sA + take * avg) * (1.0 / 1073741824.0);
    }
}

// ---------------- Final: channel deltas + stable top-3 indices ----------------
__global__ void final_kernel(const double* __restrict__ total_sum,
                             const double* __restrict__ topk_sum,
                             int* __restrict__ out) {
    __shared__ double delta[CCH];
    const int c = threadIdx.x;
    double th = 0.0, tot = 0.0;
    for (int b = 0; b < BN; ++b) {
        th  += topk_sum[b * CCH + c];
        tot += total_sum[b * CCH + c];
    }
    // ranking monotone in (mean_high - mean)
    delta[c] = th / ((double)BN * (double)KSEL) - tot / ((double)BN * (double)HWSZ);
    __syncthreads();
    if (c == 0) {
        int chosen[3];
        for (int j = 0; j < 3; ++j) {
            double bv = -1e300; int bi = 0;
            for (int i = 0; i < CCH; ++i) {
                bool skip = false;
                for (int jj = 0; jj < j; ++jj) if (chosen[jj] == i) skip = true;
                if (!skip && delta[i] > bv) { bv = delta[i]; bi = i; }  // strict >: lower idx wins ties
            }
            chosen[j] = bi;
            out[j] = bi;
        }
    }
}

extern "C" void kernel_launch(void* const* d_in, const int* in_sizes, int n_in,
                              void* d_out, int out_size, void* d_ws, size_t ws_size,
                              hipStream_t stream) {
    const float* hsi = (const float*)d_in[0];
    const float* w   = (const float*)d_in[1];
    int* out = (int*)d_out;

    char* ws = (char*)d_ws;
    double* total_sum = (double*)(ws);          // 512*8 = 4 KB
    double* topk_sum  = (double*)(ws + 4096);   // 4 KB

    hipLaunchKernelGGL(passA_kernel, dim3(NG), dim3(NT), 0, stream, hsi, w, total_sum, topk_sum);
    hipLaunchKernelGGL(final_kernel, dim3(1), dim3(CCH), 0, stream, total_sum, topk_sum, out);
}

// Round 5
// 225.980 us; speedup vs baseline: 1.1034x; 1.1034x over previous
//
#include <hip/hip_runtime.h>

#define HWSZ 65536      // H*W
#define KSEL 32768u     // int(0.5*H*W)
#define CCH  128        // channels
#define BN   4          // batch
#define NG   (CCH * BN) // 512 groups; group g = b*CCH + c, contiguous HWSZ floats
#define NT   1024       // threads per block (16 waves) -> 2 blocks/CU = 32 waves/CU
#define NW   (NT / 64)  // 16 waves
#define ITER (HWSZ / 4 / NT)   // 16 float4 iterations per pass

#define NB1  12                // coarse bins: b1 = q>>25 in [0,11] (e < 0.375 always)
#define NB2  1024              // fine bins inside boundary coarse bin (12K effective)
#define QC   (-744261120.0f)   // -ln(2) * 2^30: q = (u32)(f1*log2(f1)*QC + 0.5)
#define SUMMASK ((1ull << 47) - 1ull)   // q30 sum bits[46:0], count bits[63:47]

// Two streaming passes, zero LDS ops in the phase-1 hot loop, no scratch spills.
// Phase 1 (HBM): exact q30 total (register u64) + coarse 12-bin count hist in a
// u64 register SWAR (5-bit fields, flushed to u16-packed accumulators every 16
// elements; max field 16 < 31). Outer loop is #pragma unroll 1 so at most 4
// float4 loads are in flight -> fits the 64-VGPR budget of 8 waves/EU (round-4
// full unroll spilled: WRITE_SIZE 65 MB of scratch).
// Phase 2 (L3 re-read): exact q30 sum of coarse bins > cb in registers;
// boundary-bin elements go to a 1024-fine-bin packed (cnt<<47|q30) LDS atomic
// hist (fire-and-forget). Binning (q / b1 / fbin) bit-identical to the
// verified round-3/4 kernels.
__global__ void __launch_bounds__(NT, 8) passA_kernel(
    const float* __restrict__ hsi, const float* __restrict__ wp,
    double* __restrict__ total_sum, double* __restrict__ topk_sum) {
    __shared__ unsigned long long hist2[NB2];      // 8 KB packed fine hist
    __shared__ unsigned wred[NW * 6];              // 384 B wave-level coarse counts
    __shared__ unsigned cnt1[NB1];                 // 48 B
    __shared__ unsigned long long wtot[NW];        // 128 B
    __shared__ unsigned long long whigh[NW];       // 128 B
    __shared__ int s_cb;
    __shared__ unsigned s_acc;                     // exact count strictly above bin cb
    __shared__ int s_fb;
    // total ~10 KB LDS

    const int g    = blockIdx.x;
    const int tid  = threadIdx.x;
    const int lane = tid & 63;
    const int wid  = tid >> 6;
    const float w  = wp[0];

    hist2[tid] = 0ull;                             // NT == NB2; consumed after 2 barriers

    const float4* __restrict__ src = (const float4*)(hsi + (size_t)g * HWSZ);

    // ---- Phase 1: HBM stream — exact q30 total + register-SWAR coarse hist ----
    unsigned long long tot = 0ull;
    unsigned acc0 = 0u, acc1 = 0u, acc2 = 0u, acc3 = 0u, acc4 = 0u, acc5 = 0u;

    #pragma unroll 1
    for (int o = 0; o < 4; ++o) {                  // real loop: caps regs in flight
        unsigned long long sw = 0ull;              // 12 x 5-bit count fields
        #pragma unroll
        for (int ii = 0; ii < 4; ++ii) {
            float4 v = src[(o * 4 + ii) * NT + tid];
            unsigned qs = 0u;                      // 4*q < 2^31: safe u32 batch
            #pragma unroll
            for (int j = 0; j < 4; ++j) {
                float f1 = (&v.x)[j] * w;
                float m  = f1 * __log2f(f1);       // v_log_f32 + v_mul
                unsigned q = (unsigned)fmaf(m, QC, 0.5f);  // e*2^30, q < 2^29
                qs += q;
                unsigned b1 = q >> 25;             // coarse bin, <= 11 always
                sw += 1ull << (b1 * 5);            // register SWAR count
            }
            tot += qs;
        }
        // flush SWAR (16 elements counted; max field 16 < 31)
        acc0 += (unsigned)( sw        & 31u) | ((unsigned)((sw >>  5) & 31u) << 16);
        acc1 += (unsigned)((sw >> 10) & 31u) | ((unsigned)((sw >> 15) & 31u) << 16);
        acc2 += (unsigned)((sw >> 20) & 31u) | ((unsigned)((sw >> 25) & 31u) << 16);
        acc3 += (unsigned)((sw >> 30) & 31u) | ((unsigned)((sw >> 35) & 31u) << 16);
        acc4 += (unsigned)((sw >> 40) & 31u) | ((unsigned)((sw >> 45) & 31u) << 16);
        acc5 += (unsigned)((sw >> 50) & 31u) | ((unsigned)((sw >> 55) & 31u) << 16);
    }

    // wave-level reductions (u16 fields: max 64 lanes * 64 = 4096 < 65536)
    {
        unsigned accv[6] = {acc0, acc1, acc2, acc3, acc4, acc5};
        #pragma unroll
        for (int k = 0; k < 6; ++k) {
            unsigned a = accv[k];
            #pragma unroll
            for (int off = 32; off > 0; off >>= 1) a += __shfl_down(a, off, 64);
            if (lane == 0) wred[wid * 6 + k] = a;
        }
    }
    #pragma unroll
    for (int off = 32; off > 0; off >>= 1) tot += __shfl_down(tot, off, 64);
    if (lane == 0) wtot[wid] = tot;
    __syncthreads();

    // ---- combine 16 waves -> cnt1[12] ----
    if (tid < NB1) {
        unsigned s = 0u;
        #pragma unroll
        for (int ww = 0; ww < NW; ++ww) {
            unsigned v = wred[ww * 6 + (tid >> 1)];
            s += (tid & 1) ? (v >> 16) : (v & 0xFFFFu);
        }
        cnt1[tid] = s;
    }
    __syncthreads();

    // ---- locate level-1 boundary bin cb (scan from the top; 12 bins) ----
    if (tid == 0) {
        unsigned acc = 0u;
        int b = NB1 - 1;
        for (; b > 0; --b) {
            unsigned c = cnt1[b];
            if (acc + c >= KSEL) break;
            acc += c;
        }
        s_cb = b;
        s_acc = acc;
    }
    __syncthreads();
    const unsigned cb = (unsigned)s_cb;

    // ---- Phase 2: L3-resident re-read — exact high sum + fine hist inside cb ----
    unsigned long long hsum = 0ull;
    #pragma unroll 1
    for (int o = 0; o < 4; ++o) {
        #pragma unroll
        for (int ii = 0; ii < 4; ++ii) {
            float4 v = src[(o * 4 + ii) * NT + tid];
            unsigned qs = 0u;
            #pragma unroll
            for (int j = 0; j < 4; ++j) {
                float f1 = (&v.x)[j] * w;
                float m  = f1 * __log2f(f1);
                unsigned q = (unsigned)fmaf(m, QC, 0.5f);  // bit-identical to phase 1
                unsigned b1 = q >> 25;
                qs += (b1 > cb) ? q : 0u;
                if (b1 == cb) {
                    unsigned fbin = (q >> 15) & (NB2 - 1); // exact: 2^25/2^15 = 1024
                    atomicAdd(&hist2[fbin], (1ull << 47) | (unsigned long long)q);
                }
            }
            hsum += qs;
        }
    }
    #pragma unroll
    for (int off = 32; off > 0; off >>= 1) hsum += __shfl_down(hsum, off, 64);
    if (lane == 0) whigh[wid] = hsum;
    __syncthreads();

    // ---- in-place parallel suffix scan on packed hist2 (cnt 17b ok, sum < 2^45) ----
    for (int off = 1; off < NB2; off <<= 1) {
        unsigned long long a = hist2[tid];
        unsigned long long b = (tid + off < NB2) ? hist2[tid + off] : 0ull;
        __syncthreads();
        hist2[tid] = a + b;
        __syncthreads();
    }
    const unsigned needed = KSEL - s_acc;          // >= 1 by construction of cb
    {
        unsigned c0 = (unsigned)(hist2[tid] >> 47);
        unsigned c1 = (tid == NB2 - 1) ? 0u : (unsigned)(hist2[tid + 1] >> 47);
        if (c0 >= needed && c1 < needed) s_fb = tid;   // unique crossing: sufc non-increasing
    }
    __syncthreads();

    if (tid == 0) {
        unsigned long long tt = 0ull, hh = 0ull;
        #pragma unroll
        for (int i = 0; i < NW; ++i) { tt += wtot[i]; hh += whigh[i]; }
        total_sum[g] = (double)tt * (1.0 / 1073741824.0);

        const int fb = s_fb;
        unsigned long long above = (fb < NB2 - 1) ? hist2[fb + 1] : 0ull;
        unsigned cA = (unsigned)(above >> 47);
        unsigned long long sA = above & SUMMASK;
        unsigned long long cur = hist2[fb];
        unsigned cf = (unsigned)(cur >> 47) - cA;
        unsigned long long sf = (cur & SUMMASK) - sA;
        // boundary fine bin: (needed-cA) items at the bin's average value.
        double take = (double)(needed - cA);
        double avg  = (cf > 0u) ? ((double)sf / (double)cf) : 0.0;
        topk_sum[g] = ((double)hh + (double)sA + take * avg) * (1.0 / 1073741824.0);
    }
}

// ---------------- Final: channel deltas + stable top-3 indices ----------------
__global__ void final_kernel(const double* __restrict__ total_sum,
                             const double* __restrict__ topk_sum,
                             int* __restrict__ out) {
    __shared__ double delta[CCH];
    const int c = threadIdx.x;
    double th = 0.0, tot = 0.0;
    for (int b = 0; b < BN; ++b) {
        th  += topk_sum[b * CCH + c];
        tot += total_sum[b * CCH + c];
    }
    // ranking monotone in (mean_high - mean)
    delta[c] = th / ((double)BN * (double)KSEL) - tot / ((double)BN * (double)HWSZ);
    __syncthreads();
    if (c == 0) {
        int chosen[3];
        for (int j = 0; j < 3; ++j) {
            double bv = -1e300; int bi = 0;
            for (int i = 0; i < CCH; ++i) {
                bool skip = false;
                for (int jj = 0; jj < j; ++jj) if (chosen[jj] == i) skip = true;
                if (!skip && delta[i] > bv) { bv = delta[i]; bi = i; }  // strict >: lower idx wins ties
            }
            chosen[j] = bi;
            out[j] = bi;
        }
    }
}

extern "C" void kernel_launch(void* const* d_in, const int* in_sizes, int n_in,
                              void* d_out, int out_size, void* d_ws, size_t ws_size,
                              hipStream_t stream) {
    const float* hsi = (const float*)d_in[0];
    const float* w   = (const float*)d_in[1];
    int* out = (int*)d_out;

    char* ws = (char*)d_ws;
    double* total_sum = (double*)(ws);          // 512*8 = 4 KB
    double* topk_sum  = (double*)(ws + 4096);   // 4 KB

    hipLaunchKernelGGL(passA_kernel, dim3(NG), dim3(NT), 0, stream, hsi, w, total_sum, topk_sum);
    hipLaunchKernelGGL(final_kernel, dim3(1), dim3(CCH), 0, stream, total_sum, topk_sum, out);
}